// Round 4
// baseline (128.223 us; speedup 1.0000x reference)
//
#include <hip/hip_runtime.h>
#include <hip/hip_bf16.h>

// FMICLLoss: out = -mean(s_pos) + ALPHA * ( sum_{i!=j} exp(-d2_ij/2) / (N(N-1)) + EPS )
// N=8192, D=256, SIGMA=1 (inv2s2=0.5), ALPHA=1.5, EPS=1e-8, NORM_EPS=1e-12.
//
// Round 4:
//  - pair_kernel moved to MX-fp8: mfma_scale_f32_16x16x128_f8f6f4 with unit
//    E8M0 scales (0x7F). 2x MFMA rate vs bf16, half the staging bytes.
//    Numerics: fp8 quant -> dot err rms ~1.6e-3 -> bias on mean ~1e-6,
//    threshold is 1.1e-2. K=256 = 2 chunks of K=128 (4 barrier drains vs 8).
//  - XOR-swizzled LDS (stored 16B-block = logical ^ (row&7)) applied on the
//    DMA source address; conflict-free ds_read_b128, no padding.
//  - finalize fused into pair via device-scope completion counter (saves a
//    launch); counter zeroed by norm_kernel (previous dispatch in stream).
//  NOTE: ~50us of dur_us is harness overhead (268MB ws re-poison fill @45us
//  + d_in restore) — outside kernel control.

#define N_ROWS 8192
#define DIM    256
#define LOG2E  1.4426950408889634f
#define NBLK   2080

typedef __attribute__((ext_vector_type(8))) int   int8v;
typedef __attribute__((ext_vector_type(4))) float f32x4;

#define GLDS16(gptr, lptr) \
  __builtin_amdgcn_global_load_lds((const __attribute__((address_space(1))) void*)(gptr), \
                                   (__attribute__((address_space(3))) void*)(lptr), 16, 0, 0)

// ---------------------------------------------------------------------------
// Kernel 1: row-normalize z1,z2; write z1n8 (fp8 e4m3) + hl[i]=0.5*log2e*||z||^2;
// per-block s_pos partial; zero the completion counter for pair_kernel.
// ---------------------------------------------------------------------------
__global__ __launch_bounds__(256) void norm_kernel(
    const float* __restrict__ z1, const float* __restrict__ z2,
    unsigned char* __restrict__ z1n8, float* __restrict__ hl,
    float* __restrict__ spos_part, unsigned* __restrict__ counter) {

    int tid  = threadIdx.x;
    int wave = tid >> 6, lane = tid & 63;
    int row  = blockIdx.x * 4 + wave;

    const float4 a = *(const float4*)(z1 + (size_t)row * DIM + lane * 4);
    const float4 b = *(const float4*)(z2 + (size_t)row * DIM + lane * 4);

    float s1 = a.x*a.x + a.y*a.y + a.z*a.z + a.w*a.w;
    float s2 = b.x*b.x + b.y*b.y + b.z*b.z + b.w*b.w;
    #pragma unroll
    for (int off = 32; off; off >>= 1) {
        s1 += __shfl_xor(s1, off);
        s2 += __shfl_xor(s2, off);
    }
    float m1 = fmaxf(sqrtf(s1), 1e-12f);
    float m2 = fmaxf(sqrtf(s2), 1e-12f);

    float4 an = make_float4(a.x/m1, a.y/m1, a.z/m1, a.w/m1);
    float4 bn = make_float4(b.x/m2, b.y/m2, b.z/m2, b.w/m2);

    // positive-pair distance (fp32-exact path, matches reference closely)
    float dx = an.x - bn.x, dy = an.y - bn.y, dz = an.z - bn.z, dw = an.w - bn.w;
    float dp = dx*dx + dy*dy + dz*dz + dw*dw;
    #pragma unroll
    for (int off = 32; off; off >>= 1) dp += __shfl_xor(dp, off);

    // pack 4 fp8 e4m3 (OCP on gfx950) and store 4B/lane (coalesced 256B/row)
    int lo = __builtin_amdgcn_cvt_pk_fp8_f32(an.x, an.y, 0,  false);
    int pk = __builtin_amdgcn_cvt_pk_fp8_f32(an.z, an.w, lo, true);
    ((int*)(z1n8 + (size_t)row * DIM))[lane] = pk;

    __shared__ float sp[4];
    if (lane == 0) {
        float sqn = s1 / (m1 * m1);                      // ||z1n||^2 (fp32-exact)
        hl[row] = 0.5f * LOG2E * sqn;
        sp[wave] = logf(expf(-dp * 0.5f) + 1e-8f) + 1.0f;  // s_pos
    }
    __syncthreads();
    if (tid == 0)
        spos_part[blockIdx.x] = sp[0] + sp[1] + sp[2] + sp[3];
    if (blockIdx.x == 0 && tid == 0)
        *counter = 0;        // plain store; flushed at kernel end (stream order)
}

// ---------------------------------------------------------------------------
// Kernel 2: fused fp8 Z·Z^T + exp-sum epilogue, upper block-triangle only,
// plus fused final reduction (last block via device-scope counter).
// 128x128 tile / block, 4 waves (2x2 of 64x64), mfma_scale 16x16x128 fp8,
// K = 2 chunks of 128. DMA staging, XOR-swizzled LDS.
// ---------------------------------------------------------------------------
__global__ __launch_bounds__(256) void pair_kernel(
    const unsigned char* __restrict__ z1n8, const float* __restrict__ hl,
    const float* __restrict__ spos_part, float* __restrict__ negp_part,
    unsigned* __restrict__ counter, float* __restrict__ out) {

    // triangular decode: block t -> (bi, bj), bi <= bj, NBLK blocks
    int t = blockIdx.x;
    int u = NBLK - 1 - t;
    int k = (int)((sqrtf(8.0f * (float)u + 1.0f) - 1.0f) * 0.5f);
    while ((k + 1) * (k + 2) / 2 <= u) ++k;
    while (k * (k + 1) / 2 > u) --k;
    int bi = 63 - k;
    int bj = 63 - (u - k * (k + 1) / 2);

    __shared__ unsigned char A[128 * 128];   // 16 KB fp8, chunk-local, swizzled
    __shared__ unsigned char B[128 * 128];   // 16 KB
    __shared__ float red[4];
    __shared__ int   isLast;

    int tid  = threadIdx.x;
    int wave = tid >> 6, lane = tid & 63;
    int wr = wave >> 1, wc = wave & 1;
    int quad = lane >> 4, colL = lane & 15;

    // DMA source addressing: lane l = (rl, cl); stages row base+rl, stored
    // 16B-block cl; must fetch logical block (cl ^ rl)  (row&7 == rl&7)
    int rl = lane >> 3, cl = lane & 7;
    const unsigned char* gA = z1n8 + (size_t)(bi * 128 + wave * 32 + rl) * DIM + ((cl ^ rl) << 4);
    const unsigned char* gB = z1n8 + (size_t)(bj * 128 + wave * 32 + rl) * DIM + ((cl ^ rl) << 4);
    unsigned char* lA = &A[(wave * 32) * 128];
    unsigned char* lB = &B[(wave * 32) * 128];

    f32x4 accf[4][4] = {};

    for (int kc = 0; kc < 2; ++kc) {
        __syncthreads();                     // prev chunk's reads done
        #pragma unroll
        for (int q = 0; q < 4; ++q) {        // 8 rows per issue, 32 rows/wave
            GLDS16(gA + kc * 128 + q * 8 * DIM, lA + q * 8 * 128);
            GLDS16(gB + kc * 128 + q * 8 * DIM, lB + q * 8 * 128);
        }
        __syncthreads();                     // drains vmcnt -> DMA data visible

        // fragments: lane holds A[m=colL][k = quad*32 .. +32) -> 2x ds_read_b128
        int8v af[4], bf[4];
        #pragma unroll
        for (int m = 0; m < 4; ++m) {
            int ar = wr * 64 + m * 16 + colL;
            int base = ar * 128;
            int b0 = ((quad * 2)     ^ (ar & 7)) << 4;
            int b1 = ((quad * 2 + 1) ^ (ar & 7)) << 4;
            union { int8v v; uint4 q[2]; } u8;
            u8.q[0] = *(const uint4*)&A[base + b0];
            u8.q[1] = *(const uint4*)&A[base + b1];
            af[m] = u8.v;
        }
        #pragma unroll
        for (int n = 0; n < 4; ++n) {
            int br = wc * 64 + n * 16 + colL;
            int base = br * 128;
            int b0 = ((quad * 2)     ^ (br & 7)) << 4;
            int b1 = ((quad * 2 + 1) ^ (br & 7)) << 4;
            union { int8v v; uint4 q[2]; } u8;
            u8.q[0] = *(const uint4*)&B[base + b0];
            u8.q[1] = *(const uint4*)&B[base + b1];
            bf[n] = u8.v;
        }
        #pragma unroll
        for (int m = 0; m < 4; ++m)
            #pragma unroll
            for (int n = 0; n < 4; ++n)
                accf[m][n] = __builtin_amdgcn_mfma_scale_f32_16x16x128_f8f6f4(
                    af[m], bf[n], accf[m][n],
                    0 /*fmtA=fp8*/, 0 /*fmtB=fp8*/,
                    0, 0x7F7F7F7F,   // scale A = 1.0 (E8M0 127)
                    0, 0x7F7F7F7F);  // scale B = 1.0
    }

    // epilogue: term = exp2(min(dot*log2e - h_i - h_j, 0)), skip i==j
    float local = 0.0f;
    float hjn[4];
    #pragma unroll
    for (int n = 0; n < 4; ++n)
        hjn[n] = hl[bj * 128 + wc * 64 + n * 16 + colL];

    if (bi != bj) {
        #pragma unroll
        for (int m = 0; m < 4; ++m) {
            #pragma unroll
            for (int reg = 0; reg < 4; ++reg) {
                float hi = hl[bi * 128 + wr * 64 + m * 16 + quad * 4 + reg];
                #pragma unroll
                for (int n = 0; n < 4; ++n) {
                    float arg = fminf(accf[m][n][reg] * LOG2E - hi - hjn[n], 0.0f);
                    local += __builtin_amdgcn_exp2f(arg);
                }
            }
        }
        local *= 2.0f;                       // mirrored block
    } else {
        #pragma unroll
        for (int m = 0; m < 4; ++m) {
            #pragma unroll
            for (int reg = 0; reg < 4; ++reg) {
                int i = wr * 64 + m * 16 + quad * 4 + reg;
                float hi = hl[bi * 128 + i];
                #pragma unroll
                for (int n = 0; n < 4; ++n) {
                    int j = wc * 64 + n * 16 + colL;
                    float arg = fminf(accf[m][n][reg] * LOG2E - hi - hjn[n], 0.0f);
                    float e = __builtin_amdgcn_exp2f(arg);
                    local += (i == j) ? 0.0f : e;
                }
            }
        }
    }

    #pragma unroll
    for (int off = 32; off; off >>= 1) local += __shfl_down(local, off);
    if (lane == 0) red[wave] = local;
    __syncthreads();

    if (tid == 0) {
        float part = red[0] + red[1] + red[2] + red[3];
        __hip_atomic_store(&negp_part[t], part,
                           __ATOMIC_RELEASE, __HIP_MEMORY_SCOPE_AGENT);
        unsigned prev = __hip_atomic_fetch_add(counter, 1u,
                           __ATOMIC_ACQ_REL, __HIP_MEMORY_SCOPE_AGENT);
        isLast = (prev == NBLK - 1) ? 1 : 0;
    }
    __syncthreads();

    if (isLast) {                            // fused finalize (last block only)
        double s = 0.0, ng = 0.0;
        for (int i = tid; i < 2048; i += 256) s += (double)spos_part[i];
        for (int i = tid; i < NBLK; i += 256)
            ng += (double)__hip_atomic_load(&negp_part[i],
                          __ATOMIC_RELAXED, __HIP_MEMORY_SCOPE_AGENT);
        #pragma unroll
        for (int off = 32; off; off >>= 1) {
            s  += __shfl_xor(s,  off);
            ng += __shfl_xor(ng, off);
        }
        __shared__ double sd[4], nd[4];
        if (lane == 0) { sd[wave] = s; nd[wave] = ng; }
        __syncthreads();
        if (tid == 0) {
            double st = sd[0] + sd[1] + sd[2] + sd[3];
            double nt = nd[0] + nd[1] + nd[2] + nd[3];
            double mean_star = nt / (8192.0 * 8191.0) + 1e-8;
            out[0] = (float)(-st / 8192.0 + 1.5 * mean_star);
        }
    }
}

extern "C" void kernel_launch(void* const* d_in, const int* in_sizes, int n_in,
                              void* d_out, int out_size, void* d_ws, size_t ws_size,
                              hipStream_t stream) {
    const float* z1 = (const float*)d_in[0];
    const float* z2 = (const float*)d_in[1];
    float* out = (float*)d_out;

    char* ws = (char*)d_ws;
    float* hl            = (float*)ws;                                 // 32 KB
    unsigned char* z1n8  = (unsigned char*)(ws + N_ROWS * 4);          // 2 MB fp8
    float* spos_part     = (float*)(ws + N_ROWS * 4 + N_ROWS * DIM);   // 8 KB
    float* negp_part     = spos_part + 2048;                           // 8.3 KB
    unsigned* counter    = (unsigned*)(negp_part + NBLK);              // 4 B

    norm_kernel<<<N_ROWS / 4, 256, 0, stream>>>(z1, z2, z1n8, hl, spos_part, counter);
    pair_kernel<<<NBLK, 256, 0, stream>>>(z1n8, hl, spos_part, negp_part, counter, out);
}

// Round 5
// 91.340 us; speedup vs baseline: 1.4038x; 1.4038x over previous
//
#include <hip/hip_runtime.h>
#include <hip/hip_bf16.h>

// FMICLLoss: out = -mean(s_pos) + ALPHA * ( sum_{i!=j} exp(-d2_ij/2) / (N(N-1)) + EPS )
// N=8192, D=256, SIGMA=1 (inv2s2=0.5), ALPHA=1.5, EPS=1e-8, NORM_EPS=1e-12.
//
// Round 5: Round-4's fused finalize used a device-scope ACQ_REL fetch_add per
// block (2080 same-line atomics ~12.7ns serialized + agent-scope acquire =
// per-XCD L2 invalidate each time -> tile refetch stalls, MfmaUtil 5%).
// Reverted to 3 kernels, zero atomics. Kept MX-fp8 MFMA; now single-chunk:
// full K=256 tile in LDS (A+B = 64 KB) -> ONE barrier drain per block, then
// 32 mfma_scale/wave uninterrupted. XOR swizzle for 256B row stride on the
// DMA source address; conflict-free ds_read_b128.
// ~50us of dur_us is harness ws re-poison fill + input restore (untouchable).

#define N_ROWS 8192
#define DIM    256
#define LOG2E  1.4426950408889634f
#define NBLK   2080

typedef __attribute__((ext_vector_type(8))) int   int8v;
typedef __attribute__((ext_vector_type(4))) float f32x4;

#define GLDS16(gptr, lptr) \
  __builtin_amdgcn_global_load_lds((const __attribute__((address_space(1))) void*)(gptr), \
                                   (__attribute__((address_space(3))) void*)(lptr), 16, 0, 0)

// ---------------------------------------------------------------------------
// Kernel 1: row-normalize z1,z2; write z1n8 (fp8 e4m3) + hl[i]=0.5*log2e*||z||^2;
// per-block s_pos partial. One wave per row. No atomics.
// ---------------------------------------------------------------------------
__global__ __launch_bounds__(256) void norm_kernel(
    const float* __restrict__ z1, const float* __restrict__ z2,
    unsigned char* __restrict__ z1n8, float* __restrict__ hl,
    float* __restrict__ spos_part) {

    int tid  = threadIdx.x;
    int wave = tid >> 6, lane = tid & 63;
    int row  = blockIdx.x * 4 + wave;

    const float4 a = *(const float4*)(z1 + (size_t)row * DIM + lane * 4);
    const float4 b = *(const float4*)(z2 + (size_t)row * DIM + lane * 4);

    float s1 = a.x*a.x + a.y*a.y + a.z*a.z + a.w*a.w;
    float s2 = b.x*b.x + b.y*b.y + b.z*b.z + b.w*b.w;
    #pragma unroll
    for (int off = 32; off; off >>= 1) {
        s1 += __shfl_xor(s1, off);
        s2 += __shfl_xor(s2, off);
    }
    float m1 = fmaxf(sqrtf(s1), 1e-12f);
    float m2 = fmaxf(sqrtf(s2), 1e-12f);

    float4 an = make_float4(a.x/m1, a.y/m1, a.z/m1, a.w/m1);
    float4 bn = make_float4(b.x/m2, b.y/m2, b.z/m2, b.w/m2);

    // positive-pair distance (fp32-exact path)
    float dx = an.x - bn.x, dy = an.y - bn.y, dz = an.z - bn.z, dw = an.w - bn.w;
    float dp = dx*dx + dy*dy + dz*dz + dw*dw;
    #pragma unroll
    for (int off = 32; off; off >>= 1) dp += __shfl_xor(dp, off);

    // pack 4 fp8 e4m3 (OCP) and store 4B/lane (coalesced 256B/row)
    int lo = __builtin_amdgcn_cvt_pk_fp8_f32(an.x, an.y, 0,  false);
    int pk = __builtin_amdgcn_cvt_pk_fp8_f32(an.z, an.w, lo, true);
    ((int*)(z1n8 + (size_t)row * DIM))[lane] = pk;

    __shared__ float sp[4];
    if (lane == 0) {
        float sqn = s1 / (m1 * m1);                      // ||z1n||^2 (fp32-exact)
        hl[row] = 0.5f * LOG2E * sqn;
        sp[wave] = logf(expf(-dp * 0.5f) + 1e-8f) + 1.0f;  // s_pos
    }
    __syncthreads();
    if (tid == 0)
        spos_part[blockIdx.x] = sp[0] + sp[1] + sp[2] + sp[3];
}

// ---------------------------------------------------------------------------
// Kernel 2: fused fp8 Z·Z^T + exp-sum epilogue, upper block-triangle only.
// 128x128 tile / block, 4 waves (2x2 of 64x64), mfma_scale 16x16x128 fp8.
// Full-K LDS tiles (A,B = 32 KB each), ONE barrier drain, XOR-swizzled.
// Writes one fp32 partial per block. No atomics.
// ---------------------------------------------------------------------------
__global__ __launch_bounds__(256) void pair_kernel(
    const unsigned char* __restrict__ z1n8, const float* __restrict__ hl,
    float* __restrict__ negp_part) {

    // triangular decode: block t -> (bi, bj), bi <= bj, NBLK blocks
    int t = blockIdx.x;
    int u = NBLK - 1 - t;
    int k = (int)((sqrtf(8.0f * (float)u + 1.0f) - 1.0f) * 0.5f);
    while ((k + 1) * (k + 2) / 2 <= u) ++k;
    while (k * (k + 1) / 2 > u) --k;
    int bi = 63 - k;
    int bj = 63 - (u - k * (k + 1) / 2);

    __shared__ unsigned char A[128 * 256];   // 32 KB fp8, full K, swizzled
    __shared__ unsigned char B[128 * 256];   // 32 KB
    __shared__ float red[4];

    int tid  = threadIdx.x;
    int wave = tid >> 6, lane = tid & 63;
    int wr = wave >> 1, wc = wave & 1;
    int quad = lane >> 4, colL = lane & 15;

    // DMA staging: per issue, 64 lanes x 16B = 4 rows of 256B. lane=(rl,cl):
    // rl = lane>>4 (row within group-of-4), cl = lane&15 (stored 16B block).
    // Stored block cl must receive logical block cl ^ (row&7);
    // row&7 = (q&1)*4 + rl for issue q. Two swizzled base pointers (q even/odd).
    int rl = lane >> 4, cl = lane & 15;
    const unsigned char* gAe = z1n8 + (size_t)(bi*128 + wave*32     + rl) * DIM + ((cl ^  rl     ) << 4);
    const unsigned char* gAo = z1n8 + (size_t)(bi*128 + wave*32 + 4 + rl) * DIM + ((cl ^ (rl + 4)) << 4);
    const unsigned char* gBe = z1n8 + (size_t)(bj*128 + wave*32     + rl) * DIM + ((cl ^  rl     ) << 4);
    const unsigned char* gBo = z1n8 + (size_t)(bj*128 + wave*32 + 4 + rl) * DIM + ((cl ^ (rl + 4)) << 4);
    unsigned char* lA = &A[(wave * 32) * 256];
    unsigned char* lB = &B[(wave * 32) * 256];

    #pragma unroll
    for (int h = 0; h < 4; ++h) {            // issues q=2h (even), 2h+1 (odd)
        GLDS16(gAe + h * 8 * DIM, lA + (2*h    ) * 1024);
        GLDS16(gAo + h * 8 * DIM, lA + (2*h + 1) * 1024);
        GLDS16(gBe + h * 8 * DIM, lB + (2*h    ) * 1024);
        GLDS16(gBo + h * 8 * DIM, lB + (2*h + 1) * 1024);
    }
    __syncthreads();                         // single drain: DMA data visible

    f32x4 accf[4][4] = {};
    const int c7 = colL & 7;

    #pragma unroll
    for (int ks = 0; ks < 2; ++ks) {         // two K=128 steps, no barriers
        int8v af[4], bf[4];
        #pragma unroll
        for (int m = 0; m < 4; ++m) {
            int base = (wr * 64 + m * 16 + colL) * 256;
            int sb0 = ks * 8 + ((quad * 2    ) ^ c7);
            int sb1 = ks * 8 + ((quad * 2 + 1) ^ c7);
            union { int8v v; uint4 q[2]; } u8;
            u8.q[0] = *(const uint4*)&A[base + (sb0 << 4)];
            u8.q[1] = *(const uint4*)&A[base + (sb1 << 4)];
            af[m] = u8.v;
        }
        #pragma unroll
        for (int n = 0; n < 4; ++n) {
            int base = (wc * 64 + n * 16 + colL) * 256;
            int sb0 = ks * 8 + ((quad * 2    ) ^ c7);
            int sb1 = ks * 8 + ((quad * 2 + 1) ^ c7);
            union { int8v v; uint4 q[2]; } u8;
            u8.q[0] = *(const uint4*)&B[base + (sb0 << 4)];
            u8.q[1] = *(const uint4*)&B[base + (sb1 << 4)];
            bf[n] = u8.v;
        }
        #pragma unroll
        for (int m = 0; m < 4; ++m)
            #pragma unroll
            for (int n = 0; n < 4; ++n)
                accf[m][n] = __builtin_amdgcn_mfma_scale_f32_16x16x128_f8f6f4(
                    af[m], bf[n], accf[m][n],
                    0 /*fmtA=fp8*/, 0 /*fmtB=fp8*/,
                    0, 0x7F7F7F7F,   // scale A = 1.0 (E8M0 127)
                    0, 0x7F7F7F7F);  // scale B = 1.0
    }

    // epilogue: term = exp2(min(dot*log2e - h_i - h_j, 0)), skip i==j
    float local = 0.0f;
    float hjn[4];
    #pragma unroll
    for (int n = 0; n < 4; ++n)
        hjn[n] = hl[bj * 128 + wc * 64 + n * 16 + colL];

    if (bi != bj) {
        #pragma unroll
        for (int m = 0; m < 4; ++m) {
            #pragma unroll
            for (int reg = 0; reg < 4; ++reg) {
                float hi = hl[bi * 128 + wr * 64 + m * 16 + quad * 4 + reg];
                #pragma unroll
                for (int n = 0; n < 4; ++n) {
                    float arg = fminf(accf[m][n][reg] * LOG2E - hi - hjn[n], 0.0f);
                    local += __builtin_amdgcn_exp2f(arg);
                }
            }
        }
        local *= 2.0f;                       // mirrored block
    } else {
        #pragma unroll
        for (int m = 0; m < 4; ++m) {
            #pragma unroll
            for (int reg = 0; reg < 4; ++reg) {
                int i = wr * 64 + m * 16 + quad * 4 + reg;
                float hi = hl[bi * 128 + i];
                #pragma unroll
                for (int n = 0; n < 4; ++n) {
                    int j = wc * 64 + n * 16 + colL;
                    float arg = fminf(accf[m][n][reg] * LOG2E - hi - hjn[n], 0.0f);
                    float e = __builtin_amdgcn_exp2f(arg);
                    local += (i == j) ? 0.0f : e;
                }
            }
        }
    }

    #pragma unroll
    for (int off = 32; off; off >>= 1) local += __shfl_down(local, off);
    if (lane == 0) red[wave] = local;
    __syncthreads();
    if (tid == 0)
        negp_part[t] = red[0] + red[1] + red[2] + red[3];
}

// ---------------------------------------------------------------------------
// Kernel 3: finalize — reduce partials in double, emit scalar.
// ---------------------------------------------------------------------------
__global__ __launch_bounds__(256) void finalize_kernel(
    const float* __restrict__ spos_part, const float* __restrict__ negp_part,
    float* __restrict__ out) {

    int tid = threadIdx.x;
    double s = 0.0, ng = 0.0;
    for (int i = tid; i < 2048; i += 256) s  += (double)spos_part[i];
    for (int i = tid; i < NBLK; i += 256) ng += (double)negp_part[i];

    #pragma unroll
    for (int off = 32; off; off >>= 1) {
        s  += __shfl_xor(s,  off);
        ng += __shfl_xor(ng, off);
    }
    __shared__ double sd[4], nd[4];
    int wave = tid >> 6, lane = tid & 63;
    if (lane == 0) { sd[wave] = s; nd[wave] = ng; }
    __syncthreads();
    if (tid == 0) {
        double st = sd[0] + sd[1] + sd[2] + sd[3];
        double nt = nd[0] + nd[1] + nd[2] + nd[3];
        double mean_star = nt / (8192.0 * 8191.0) + 1e-8;
        out[0] = (float)(-st / 8192.0 + 1.5 * mean_star);
    }
}

extern "C" void kernel_launch(void* const* d_in, const int* in_sizes, int n_in,
                              void* d_out, int out_size, void* d_ws, size_t ws_size,
                              hipStream_t stream) {
    const float* z1 = (const float*)d_in[0];
    const float* z2 = (const float*)d_in[1];
    float* out = (float*)d_out;

    char* ws = (char*)d_ws;
    float* hl            = (float*)ws;                                 // 32 KB
    unsigned char* z1n8  = (unsigned char*)(ws + N_ROWS * 4);          // 2 MB fp8
    float* spos_part     = (float*)(ws + N_ROWS * 4 + N_ROWS * DIM);   // 8 KB
    float* negp_part     = spos_part + 2048;                           // 8.3 KB

    norm_kernel<<<N_ROWS / 4, 256, 0, stream>>>(z1, z2, z1n8, hl, spos_part);
    pair_kernel<<<NBLK, 256, 0, stream>>>(z1n8, hl, negp_part);
    finalize_kernel<<<1, 256, 0, stream>>>(spos_part, negp_part, out);
}